// Round 4
// baseline (441.599 us; speedup 1.0000x reference)
//
#include <hip/hip_runtime.h>

#define SIDE 96
#define NN 9216            // SIDE*SIDE
#define BATCH 32
#define KC 32              // k-chunk staged in LDS per block
#define CPT 4              // columns per thread (one dwordx4 W load)
#define CBLK 1024          // columns per block = 4 waves * 64 lanes * CPT
#define NCB (NN / CBLK)    // 9
#define SPLIT 72           // split-K slices
#define SLICE (NN / SPLIT) // 128 = 4 KC-chunks
#define PSTRIDE ((size_t)NN * BATCH)   // bf16 elems per partial slice

__device__ __forceinline__ float clamp01(float v) {
    return fminf(fmaxf(v, 0.0f), 1.0f);
}

__device__ __forceinline__ unsigned int packbf2(float a, float b) {
    unsigned int ua = __float_as_uint(a);
    unsigned int ub = __float_as_uint(b);
    ua = (ua + 0x7fffu + ((ua >> 16) & 1u)) >> 16;   // RNE to bf16
    ub = (ub + 0x7fffu + ((ub >> 16) & 1u)) >> 16;
    return ua | (ub << 16);
}

__device__ __forceinline__ float bf2f(unsigned short u) {
    return __uint_as_float(((unsigned int)u) << 16);
}

// xt[j*32 + b] = x[b*NN + j]
__global__ __launch_bounds__(256) void k_transpose(const float* __restrict__ x,
                                                   float* __restrict__ xt) {
    int idx = blockIdx.x * 256 + threadIdx.x;
    int j = idx >> 5;
    int b = idx & 31;
    xt[idx] = x[(size_t)b * NN + j];
}

// Partial GEMM: part[s][j][b] (bf16) = sum_{k in slice s} at[k][b] * W[k][j]
// Block: 4 waves cover 1024 consecutive cols (lane owns 4 via one dwordx4 W
// load per k). Activations staged cooperatively in LDS per KC-chunk.
__global__ __launch_bounds__(256, 2) void k_gemm_part(
    const float* __restrict__ W,      // [NN][NN] row-major (k-major)
    const float* __restrict__ at,     // [NN][BATCH]
    unsigned int* __restrict__ part)  // [SPLIT][NN][BATCH/2] bf16x2
{
    __shared__ float sa[KC * BATCH];  // 4 KB

    const int tid  = threadIdx.x;
    const int wave = tid >> 6;
    const int lane = tid & 63;
    const int cb = blockIdx.x % NCB;
    const int s  = blockIdx.x / NCB;
    const int j0 = cb * CBLK + wave * 256 + lane * CPT;
    const size_t k0 = (size_t)s * SLICE;

    const float* Wp = W + k0 * NN + j0;
    const float* ap = at + k0 * BATCH;

    float acc[CPT][BATCH];
#pragma unroll
    for (int c = 0; c < CPT; ++c)
#pragma unroll
        for (int b = 0; b < BATCH; ++b) acc[c][b] = 0.0f;

    for (int kk = 0; kk < SLICE; kk += KC) {
        __syncthreads();
        // stage KC*BATCH = 1024 floats = 256 float4, one per thread
        ((float4*)sa)[tid] = ((const float4*)(ap + (size_t)kk * BATCH))[tid];
        __syncthreads();

        const float* wrow = Wp + (size_t)kk * NN;
#pragma unroll 8
        for (int u = 0; u < KC; ++u) {
            const float4 wv = *(const float4*)(wrow + (size_t)u * NN);
            const float4* a4 = (const float4*)(sa + u * BATCH);
#pragma unroll
            for (int q = 0; q < 8; ++q) {
                const float4 av = a4[q];
                acc[0][4*q+0] = fmaf(av.x, wv.x, acc[0][4*q+0]);
                acc[0][4*q+1] = fmaf(av.y, wv.x, acc[0][4*q+1]);
                acc[0][4*q+2] = fmaf(av.z, wv.x, acc[0][4*q+2]);
                acc[0][4*q+3] = fmaf(av.w, wv.x, acc[0][4*q+3]);
                acc[1][4*q+0] = fmaf(av.x, wv.y, acc[1][4*q+0]);
                acc[1][4*q+1] = fmaf(av.y, wv.y, acc[1][4*q+1]);
                acc[1][4*q+2] = fmaf(av.z, wv.y, acc[1][4*q+2]);
                acc[1][4*q+3] = fmaf(av.w, wv.y, acc[1][4*q+3]);
                acc[2][4*q+0] = fmaf(av.x, wv.z, acc[2][4*q+0]);
                acc[2][4*q+1] = fmaf(av.y, wv.z, acc[2][4*q+1]);
                acc[2][4*q+2] = fmaf(av.z, wv.z, acc[2][4*q+2]);
                acc[2][4*q+3] = fmaf(av.w, wv.z, acc[2][4*q+3]);
                acc[3][4*q+0] = fmaf(av.x, wv.w, acc[3][4*q+0]);
                acc[3][4*q+1] = fmaf(av.y, wv.w, acc[3][4*q+1]);
                acc[3][4*q+2] = fmaf(av.z, wv.w, acc[3][4*q+2]);
                acc[3][4*q+3] = fmaf(av.w, wv.w, acc[3][4*q+3]);
            }
        }
    }

    // store bf16 partials: per col 32 floats -> 16 uints -> 4 uint4
#pragma unroll
    for (int c = 0; c < CPT; ++c) {
        uint4* pp = (uint4*)(part + ((size_t)s * NN + (size_t)(j0 + c)) * (BATCH / 2));
#pragma unroll
        for (int m = 0; m < 4; ++m) {
            uint4 v;
            v.x = packbf2(acc[c][8*m+0], acc[c][8*m+1]);
            v.y = packbf2(acc[c][8*m+2], acc[c][8*m+3]);
            v.z = packbf2(acc[c][8*m+4], acc[c][8*m+5]);
            v.w = packbf2(acc[c][8*m+6], acc[c][8*m+7]);
            pp[m] = v;
        }
    }
}

// afft[pair] = clamp01( sum_s part[s][pair] ), one uint (2 bf16) per thread
__global__ __launch_bounds__(256) void k_reduce_aff(const unsigned int* __restrict__ part,
                                                    float* __restrict__ aff_t) {
    int t = blockIdx.x * 256 + threadIdx.x;     // over NN*BATCH/2
    float v0 = 0.0f, v1 = 0.0f;
    for (int s = 0; s < SPLIT; ++s) {
        unsigned int u = part[(size_t)s * (PSTRIDE / 2) + t];
        v0 += bf2f((unsigned short)(u & 0xffffu));
        v1 += bf2f((unsigned short)(u >> 16));
    }
    float2 o = make_float2(clamp01(v0), clamp01(v1));
    ((float2*)aff_t)[t] = o;
}

// Fused epilogue: reduce inhibitory bf16 partials, sparse excitatory gather
// (13 taps of the radius-2 circular mask), combine.
__global__ __launch_bounds__(256) void k_combine(
    const unsigned short* __restrict__ part,  // [SPLIT][NN][BATCH] bf16
    const float* __restrict__ aff_t,          // [NN][BATCH], clamped
    const float* __restrict__ We,             // [NN][NN]
    float* __restrict__ out)                  // [BATCH][NN]
{
    int idx = blockIdx.x * 256 + threadIdx.x;
    int j = idx >> 5;
    int b = idx & 31;

    float inh = 0.0f;
    for (int s = 0; s < SPLIT; ++s)
        inh += bf2f(part[(size_t)s * PSTRIDE + idx]);
    inh = clamp01(inh);

    int mx = j / SIDE;
    int my = j - mx * SIDE;

    const int dxs[13] = {-2,-1,-1,-1, 0, 0, 0, 0, 0, 1, 1, 1, 2};
    const int dys[13] = { 0,-1, 0, 1,-2,-1, 0, 1, 2,-1, 0, 1, 0};

    float exc = 0.0f;
#pragma unroll
    for (int t = 0; t < 13; ++t) {
        int x = mx + dxs[t];
        int y = my + dys[t];
        if ((unsigned)x < SIDE && (unsigned)y < SIDE) {
            int i = x * SIDE + y;
            float w = We[(size_t)i * NN + j];
            exc = fmaf(aff_t[(size_t)i * BATCH + b], w, exc);
        }
    }
    exc = clamp01(exc);

    float a = aff_t[idx];
    out[(size_t)b * NN + j] = clamp01(a + 0.2f * exc - 0.4f * inh);
}

extern "C" void kernel_launch(void* const* d_in, const int* in_sizes, int n_in,
                              void* d_out, int out_size, void* d_ws, size_t ws_size,
                              hipStream_t stream) {
    const float* x  = (const float*)d_in[0];  // [32][9216]
    const float* Wr = (const float*)d_in[1];  // [9216][9216]
    const float* We = (const float*)d_in[2];  // [9216][9216] sparse (radius 2)
    const float* Wi = (const float*)d_in[3];  // [9216][9216]
    float* out = (float*)d_out;               // [32][9216]

    float* xt   = (float*)d_ws;                         // NN*32 fp32
    float* afft = xt + (size_t)NN * BATCH;              // NN*32 fp32
    unsigned int* part = (unsigned int*)(afft + (size_t)NN * BATCH);
    // part: SPLIT * NN * 32 bf16 = 42.5 MB, reused by both GEMMs

    dim3 blk(256);
    dim3 grid_eb(NN * BATCH / 256);        // 1152
    dim3 grid_rd(NN * BATCH / 2 / 256);    // 576
    dim3 grid_gm(NCB * SPLIT);             // 648

    k_transpose <<<grid_eb, blk, 0, stream>>>(x, xt);
    k_gemm_part <<<grid_gm, blk, 0, stream>>>(Wr, xt, part);
    k_reduce_aff<<<grid_rd, blk, 0, stream>>>(part, afft);
    k_gemm_part <<<grid_gm, blk, 0, stream>>>(Wi, afft, part);
    k_combine   <<<grid_eb, blk, 0, stream>>>((const unsigned short*)part, afft, We, out);
}

// Round 5
// 251.127 us; speedup vs baseline: 1.7585x; 1.7585x over previous
//
#include <hip/hip_runtime.h>

#define SIDE 96
#define NN 9216            // SIDE*SIDE
#define BATCH 32
#define KC 64              // k-chunk staged in LDS
#define CPT 4              // columns per thread (one dwordx4 W load)
#define HB 16              // batches per lane (half-wave split)
#define CBLK 512           // cols per block = 4 waves * 32 * CPT
#define NCB (NN / CBLK)    // 18
#define SPLIT 72           // split-K slices
#define SLICE (NN / SPLIT) // 128 = 2 KC-chunks
#define PSTRIDE ((size_t)NN * BATCH)   // bf16 elems per partial slice

__device__ __forceinline__ float clamp01(float v) {
    return fminf(fmaxf(v, 0.0f), 1.0f);
}

__device__ __forceinline__ unsigned int packbf2(float a, float b) {
    unsigned int ua = __float_as_uint(a);
    unsigned int ub = __float_as_uint(b);
    ua = (ua + 0x7fffu + ((ua >> 16) & 1u)) >> 16;   // RNE to bf16
    ub = (ub + 0x7fffu + ((ub >> 16) & 1u)) >> 16;
    return ua | (ub << 16);
}

__device__ __forceinline__ float bf2f(unsigned short u) {
    return __uint_as_float(((unsigned int)u) << 16);
}

// xt[j*32 + b] = x[b*NN + j]
__global__ __launch_bounds__(256) void k_transpose(const float* __restrict__ x,
                                                   float* __restrict__ xt) {
    int idx = blockIdx.x * 256 + threadIdx.x;
    int j = idx >> 5;
    int b = idx & 31;
    xt[idx] = x[(size_t)b * NN + j];
}

// Partial GEMM: part[s][j][b] (bf16) = sum_{k in slice s} at[k][b] * W[k][j]
// Half-wave batch split: lane&31 picks 4 consecutive cols, lane>>5 picks
// batch half -> acc is 64 regs. W dwordx4 address identical across halves
// (coalesced + dedup); activation ds_read_b128 has 2 distinct addrs/wave
// (free 2-way). W loads software-pipelined in 8-wide register groups.
__global__ __launch_bounds__(256, 2) void k_gemm_part(
    const float* __restrict__ W,      // [NN][NN] row-major (k-major)
    const float* __restrict__ at,     // [NN][BATCH]
    unsigned int* __restrict__ part)  // [SPLIT][NN][BATCH/2] bf16x2
{
    __shared__ float sa[KC * BATCH];  // 8 KB

    const int tid  = threadIdx.x;
    const int wave = tid >> 6;
    const int lane = tid & 63;
    const int hl   = lane & 31;
    const int half = lane >> 5;
    const int b0   = half * HB;
    const int cb = blockIdx.x % NCB;
    const int s  = blockIdx.x / NCB;
    const int j0 = cb * CBLK + wave * 128 + hl * CPT;
    const size_t k0 = (size_t)s * SLICE;

    const float* Wp = W + k0 * NN + j0;
    const float* ap = at + k0 * BATCH;

    float acc[CPT][HB];
#pragma unroll
    for (int c = 0; c < CPT; ++c)
#pragma unroll
        for (int b = 0; b < HB; ++b) acc[c][b] = 0.0f;

    for (int kk = 0; kk < SLICE; kk += KC) {
        __syncthreads();
        // stage KC*BATCH = 2048 floats = 512 float4, two per thread
        {
            const float4* src = (const float4*)(ap + (size_t)kk * BATCH);
            ((float4*)sa)[tid]       = src[tid];
            ((float4*)sa)[tid + 256] = src[tid + 256];
        }
        __syncthreads();

        const float* wrow = Wp + (size_t)kk * NN;

        float4 wcur[8], wnxt[8];
#pragma unroll
        for (int g = 0; g < 8; ++g)
            wcur[g] = *(const float4*)(wrow + (size_t)g * NN);

#pragma unroll
        for (int ug = 0; ug < KC; ug += 8) {
            // issue next group's loads before this group's FMA block
            if (ug + 8 < KC) {
#pragma unroll
                for (int g = 0; g < 8; ++g)
                    wnxt[g] = *(const float4*)(wrow + (size_t)(ug + 8 + g) * NN);
            }
#pragma unroll
            for (int g = 0; g < 8; ++g) {
                const int u = ug + g;
                const float4 wv = wcur[g];
                const float4* a4 = (const float4*)(sa + u * BATCH + b0);
#pragma unroll
                for (int q = 0; q < 4; ++q) {
                    const float4 av = a4[q];
                    acc[0][4*q+0] = fmaf(av.x, wv.x, acc[0][4*q+0]);
                    acc[0][4*q+1] = fmaf(av.y, wv.x, acc[0][4*q+1]);
                    acc[0][4*q+2] = fmaf(av.z, wv.x, acc[0][4*q+2]);
                    acc[0][4*q+3] = fmaf(av.w, wv.x, acc[0][4*q+3]);
                    acc[1][4*q+0] = fmaf(av.x, wv.y, acc[1][4*q+0]);
                    acc[1][4*q+1] = fmaf(av.y, wv.y, acc[1][4*q+1]);
                    acc[1][4*q+2] = fmaf(av.z, wv.y, acc[1][4*q+2]);
                    acc[1][4*q+3] = fmaf(av.w, wv.y, acc[1][4*q+3]);
                    acc[2][4*q+0] = fmaf(av.x, wv.z, acc[2][4*q+0]);
                    acc[2][4*q+1] = fmaf(av.y, wv.z, acc[2][4*q+1]);
                    acc[2][4*q+2] = fmaf(av.z, wv.z, acc[2][4*q+2]);
                    acc[2][4*q+3] = fmaf(av.w, wv.z, acc[2][4*q+3]);
                    acc[3][4*q+0] = fmaf(av.x, wv.w, acc[3][4*q+0]);
                    acc[3][4*q+1] = fmaf(av.y, wv.w, acc[3][4*q+1]);
                    acc[3][4*q+2] = fmaf(av.z, wv.w, acc[3][4*q+2]);
                    acc[3][4*q+3] = fmaf(av.w, wv.w, acc[3][4*q+3]);
                }
            }
#pragma unroll
            for (int g = 0; g < 8; ++g) wcur[g] = wnxt[g];
        }
    }

    // store bf16 partials: per col, this lane's 16 batch values = 2 uint4
#pragma unroll
    for (int c = 0; c < CPT; ++c) {
        unsigned int* pp = part + ((size_t)s * NN + (size_t)(j0 + c)) * (BATCH / 2)
                         + half * (HB / 2);
        uint4 v0, v1;
        v0.x = packbf2(acc[c][ 0], acc[c][ 1]);
        v0.y = packbf2(acc[c][ 2], acc[c][ 3]);
        v0.z = packbf2(acc[c][ 4], acc[c][ 5]);
        v0.w = packbf2(acc[c][ 6], acc[c][ 7]);
        v1.x = packbf2(acc[c][ 8], acc[c][ 9]);
        v1.y = packbf2(acc[c][10], acc[c][11]);
        v1.z = packbf2(acc[c][12], acc[c][13]);
        v1.w = packbf2(acc[c][14], acc[c][15]);
        *(uint4*)pp       = v0;
        *(uint4*)(pp + 4) = v1;
    }
}

// afft[pair] = clamp01( sum_s part[s][pair] ), one uint (2 bf16) per thread
__global__ __launch_bounds__(256) void k_reduce_aff(const unsigned int* __restrict__ part,
                                                    float* __restrict__ aff_t) {
    int t = blockIdx.x * 256 + threadIdx.x;     // over NN*BATCH/2
    float v0 = 0.0f, v1 = 0.0f;
    for (int s = 0; s < SPLIT; ++s) {
        unsigned int u = part[(size_t)s * (PSTRIDE / 2) + t];
        v0 += bf2f((unsigned short)(u & 0xffffu));
        v1 += bf2f((unsigned short)(u >> 16));
    }
    ((float2*)aff_t)[t] = make_float2(clamp01(v0), clamp01(v1));
}

// Fused epilogue: reduce inhibitory bf16 partials, sparse excitatory gather
// (13 taps of the radius-2 circular mask), combine.
__global__ __launch_bounds__(256) void k_combine(
    const unsigned short* __restrict__ part,  // [SPLIT][NN][BATCH] bf16
    const float* __restrict__ aff_t,          // [NN][BATCH], clamped
    const float* __restrict__ We,             // [NN][NN]
    float* __restrict__ out)                  // [BATCH][NN]
{
    int idx = blockIdx.x * 256 + threadIdx.x;
    int j = idx >> 5;
    int b = idx & 31;

    float inh = 0.0f;
    for (int s = 0; s < SPLIT; ++s)
        inh += bf2f(part[(size_t)s * PSTRIDE + idx]);
    inh = clamp01(inh);

    int mx = j / SIDE;
    int my = j - mx * SIDE;

    const int dxs[13] = {-2,-1,-1,-1, 0, 0, 0, 0, 0, 1, 1, 1, 2};
    const int dys[13] = { 0,-1, 0, 1,-2,-1, 0, 1, 2,-1, 0, 1, 0};

    float exc = 0.0f;
#pragma unroll
    for (int t = 0; t < 13; ++t) {
        int x = mx + dxs[t];
        int y = my + dys[t];
        if ((unsigned)x < SIDE && (unsigned)y < SIDE) {
            int i = x * SIDE + y;
            float w = We[(size_t)i * NN + j];
            exc = fmaf(aff_t[(size_t)i * BATCH + b], w, exc);
        }
    }
    exc = clamp01(exc);

    float a = aff_t[idx];
    out[(size_t)b * NN + j] = clamp01(a + 0.2f * exc - 0.4f * inh);
}

extern "C" void kernel_launch(void* const* d_in, const int* in_sizes, int n_in,
                              void* d_out, int out_size, void* d_ws, size_t ws_size,
                              hipStream_t stream) {
    const float* x  = (const float*)d_in[0];  // [32][9216]
    const float* Wr = (const float*)d_in[1];  // [9216][9216]
    const float* We = (const float*)d_in[2];  // [9216][9216] sparse (radius 2)
    const float* Wi = (const float*)d_in[3];  // [9216][9216]
    float* out = (float*)d_out;               // [32][9216]

    float* xt   = (float*)d_ws;                         // NN*32 fp32
    float* afft = xt + (size_t)NN * BATCH;              // NN*32 fp32
    unsigned int* part = (unsigned int*)(afft + (size_t)NN * BATCH);
    // part: SPLIT * NN * 32 bf16 = 42.5 MB, reused by both GEMMs

    dim3 blk(256);
    dim3 grid_eb(NN * BATCH / 256);        // 1152
    dim3 grid_rd(NN * BATCH / 2 / 256);    // 576
    dim3 grid_gm(NCB * SPLIT);             // 1296

    k_transpose <<<grid_eb, blk, 0, stream>>>(x, xt);
    k_gemm_part <<<grid_gm, blk, 0, stream>>>(Wr, xt, part);
    k_reduce_aff<<<grid_rd, blk, 0, stream>>>(part, afft);
    k_gemm_part <<<grid_gm, blk, 0, stream>>>(Wi, afft, part);
    k_combine   <<<grid_eb, blk, 0, stream>>>((const unsigned short*)part, afft, We, out);
}